// Round 6
// baseline (84.436 us; speedup 1.0000x reference)
//
#include <hip/hip_runtime.h>

// PillarLayer: fused copy + per-pillar xyz center-of-mass + BEV canvas scatter.
//
// R6 structure:
//   K1 canvas_zero: zero 20.6 MB canvas, cacheable stores (L3-resident for
//      the scatter RMW).
//   K2 pillar_fused_ilp: 4 lanes per pillar, 8 float4 NT-loads per lane
//      (8 independent loads in flight -> 8x the MLP of R5's 1-load-per-thread
//      structure; 8x fewer waves, 16KB traffic per wave). Local sum of 8
//      points per lane + 2-step butterfly across the 4-lane cluster, then
//      lanes 0-2 scatter the 3 canvas planes, lane 3 writes coors/npoints.
//
// Inputs: d_in[0] pillars f32 (P,32,4); d_in[1] coors int32 (P,4) [b,x,y,z];
//         d_in[2] npoints int32 (P); d_in[3] bs; d_in[4] x_l; d_in[5] y_l.
// Output (concat f32): pillars copy | coors as f32 | npoints as f32 |
//         canvas (bs,3,y_l,x_l) with canvas[b][c][y][x] = center_c or 0.

typedef float vfloat4 __attribute__((ext_vector_type(4)));

__global__ __launch_bounds__(256) void canvas_zero(float4* __restrict__ dst, long n4) {
    long i = (long)blockIdx.x * blockDim.x + threadIdx.x;
    const long stride = (long)gridDim.x * blockDim.x;
    const float4 z = make_float4(0.f, 0.f, 0.f, 0.f);
    for (; i < n4; i += stride) dst[i] = z;   // normal stores: want L3 residency
}

// One pillar (32 points = 32 float4) per 4-lane cluster; K=8 float4s per lane.
__global__ __launch_bounds__(256) void pillar_fused_ilp(
    const vfloat4* __restrict__ pillars4,  // P*32
    const int4* __restrict__ coors4,       // P [b,x,y,z]
    const int* __restrict__ npoints,       // P
    const int* __restrict__ xlp,           // scalar x_l
    const int* __restrict__ ylp,           // scalar y_l
    vfloat4* __restrict__ out_pillars4,    // P*32
    float4* __restrict__ out_coors4,       // P
    float* __restrict__ out_np,            // P
    float* __restrict__ canvas,            // bs*3*y_l*x_l
    int P)
{
    constexpr int K = 8;                         // float4 loads per lane
    const int g = blockIdx.x * 64 + (threadIdx.x >> 2);   // pillar id
    const int r = threadIdx.x & 3;                         // lane in cluster
    if (g >= P) return;

    const long base = (long)g * 32 + r;          // float4 index; +4k walks points

    // 8 independent NT loads issued back-to-back -> high MLP. NT keeps the
    // 327 MB stream out of L2/L3 so the zeroed canvas stays cache-resident.
    vfloat4 v[K];
    #pragma unroll
    for (int k = 0; k < K; ++k)
        v[k] = __builtin_nontemporal_load(&pillars4[base + 4 * k]);

    float sx = 0.f, sy = 0.f, sz = 0.f;
    #pragma unroll
    for (int k = 0; k < K; ++k) {
        __builtin_nontemporal_store(v[k], &out_pillars4[base + 4 * k]);
        sx += v[k].x; sy += v[k].y; sz += v[k].z;
    }

    // Butterfly across the 4-lane cluster (xor 1,2): all 4 lanes get totals.
    #pragma unroll
    for (int m = 1; m <= 2; m <<= 1) {
        sx += __shfl_xor(sx, m);
        sy += __shfl_xor(sy, m);
        sz += __shfl_xor(sz, m);
    }

    const int4 c   = coors4[g];     // same addr across cluster -> broadcast
    const int npts = npoints[g];

    if (r == 3) {
        out_coors4[g] = make_float4((float)c.x, (float)c.y, (float)c.z, (float)c.w);
        out_np[g]     = (float)npts;
    } else {
        const float s   = (r == 0) ? sx : (r == 1) ? sy : sz;
        const int x_l = *xlp;
        const int y_l = *ylp;
        const long cs   = (long)y_l * (long)x_l;            // plane stride
        const long base_c = (long)c.x * 3l * cs + (long)c.z * (long)x_l + (long)c.y;
        canvas[base_c + (long)r * cs] = s / (float)npts;    // plane r via lane r
    }
}

extern "C" void kernel_launch(void* const* d_in, const int* in_sizes, int n_in,
                              void* d_out, int out_size, void* d_ws, size_t ws_size,
                              hipStream_t stream) {
    const vfloat4* pillars4 = (const vfloat4*)d_in[0];
    const int4* coors4      = (const int4*)d_in[1];
    const int* npoints      = (const int*)d_in[2];
    const int* xlp = (const int*)d_in[4];
    const int* ylp = (const int*)d_in[5];

    const int n_pillars = in_sizes[0];   // P*128
    const int n_coors   = in_sizes[1];   // P*4
    const int P         = in_sizes[2];   // pillar count

    float* out            = (float*)d_out;
    vfloat4* out_pillars4 = (vfloat4*)out;
    float* out_coors      = out + n_pillars;
    float* out_np         = out_coors + n_coors;
    float* canvas         = out_np + P;
    const long canvas_elems = (long)out_size - n_pillars - n_coors - P;  // bs*3*y_l*x_l

    // K1: zero canvas (cacheable -> L3 resident for the scatter RMW).
    const long n4 = canvas_elems >> 2;   // canvas start is 16B-aligned here
    const long zthreads = (n4 + 1) / 2;
    int zblocks = (int)((zthreads + 255) / 256);
    if (zblocks > 2048) zblocks = 2048;
    canvas_zero<<<zblocks, 256, 0, stream>>>((float4*)canvas, n4);

    // K2: fused copy + reduce + scatter. 64 pillars per 256-thread block.
    const int blocks = (P + 63) / 64;
    pillar_fused_ilp<<<blocks, 256, 0, stream>>>(
        pillars4, coors4, npoints, xlp, ylp,
        out_pillars4, (float4*)out_coors, out_np, canvas, P);
}

// Round 7
// 81.569 us; speedup vs baseline: 1.0351x; 1.0351x over previous
//
#include <hip/hip_runtime.h>

// PillarLayer: fused copy + per-pillar xyz center-of-mass + BEV canvas scatter.
//
// R7 = R3's gather structure + R5's non-temporal streaming (the missing piece
// that made R3 regress: without NT, the 327 MB pillar stream evicted the
// idx map + centers before the gather kernel could read them).
//
//   K1 idx_zero:      zero 6.9 MB cell->pillar map in d_ws (cacheable).
//   K2 pillar_fused:  NT copy pillars (stream, no cache pollution), butterfly
//                     reduce, write centers[p] compactly (cacheable) and one
//                     idx[cell]=p+1 per pillar (cacheable, cache-absorbed RMW).
//   K3 canvas_gather: stream canvas: read idx4 (L3-hit), gather centers
//                     (L3-hit), NT-store canvas full-line (written exactly
//                     once, straight to HBM, no zero pass, no RMW).
//
// Inputs: d_in[0] pillars f32 (P,32,4); d_in[1] coors int32 (P,4) [b,x,y,z];
//         d_in[2] npoints int32 (P); d_in[3] bs; d_in[4] x_l; d_in[5] y_l.
// Output (concat f32): pillars copy | coors as f32 | npoints as f32 |
//         canvas (bs,3,y_l,x_l) with canvas[b][c][y][x] = center_c or 0.

typedef float vfloat4 __attribute__((ext_vector_type(4)));

__global__ __launch_bounds__(256) void idx_zero(int4* __restrict__ dst, int n4) {
    int i = blockIdx.x * 256 + threadIdx.x;
    if (i < n4) dst[i] = make_int4(0, 0, 0, 0);
}

__global__ __launch_bounds__(256) void pillar_fused(
    const vfloat4* __restrict__ pillars4,  // P*32 (one float4 per point)
    const int4* __restrict__ coors4,       // P [b,x,y,z]
    const int* __restrict__ npoints,       // P
    const int* __restrict__ xlp,           // scalar x_l
    const int* __restrict__ ylp,           // scalar y_l
    vfloat4* __restrict__ out_pillars4,    // P*32
    float4* __restrict__ out_coors4,       // P
    float* __restrict__ out_np,            // P
    float4* __restrict__ centers,          // P (ws): divided centers, w unused
    int* __restrict__ idx,                 // bs*y_l*x_l (ws): pillar id + 1
    int P)
{
    const int group = blockIdx.x * (blockDim.x >> 5) + (threadIdx.x >> 5);
    const int lane  = threadIdx.x & 31;
    if (group >= P) return;
    const int p = group;

    // Coalesced: 32 lanes x 16B = 512B per pillar, wave64 = 1KB contiguous
    // per instruction. NT: stream 327 MB without polluting L2/L3 so the idx
    // map + centers stay cache-resident for K3.
    const vfloat4 v = __builtin_nontemporal_load(&pillars4[p * 32 + lane]);
    __builtin_nontemporal_store(v, &out_pillars4[p * 32 + lane]);

    // Reduce x,y,z over the 32 points (xor masks < 32 stay in-group on wave64).
    float sx = v.x, sy = v.y, sz = v.z;
    #pragma unroll
    for (int m = 16; m >= 1; m >>= 1) {
        sx += __shfl_xor(sx, m);
        sy += __shfl_xor(sy, m);
        sz += __shfl_xor(sz, m);
    }

    if (lane == 0) {
        const int4 c = coors4[p];
        out_coors4[p] = make_float4((float)c.x, (float)c.y, (float)c.z, (float)c.w);

        const int npts = npoints[p];
        out_np[p] = (float)npts;
        const float inv = 1.0f / (float)npts;

        centers[p] = make_float4(sx * inv, sy * inv, sz * inv, 0.f);

        const int x_l = *xlp;
        const int y_l = *ylp;
        // cell within sample b: r = y*x_l + x   (c.x=b, c.y=x, c.z=y)
        idx[c.x * (y_l * x_l) + c.z * x_l + c.y] = p + 1;
    }
}

// One thread per 4 canvas cells of one (b,y,x) slice; writes 3 c-planes.
__global__ __launch_bounds__(256) void canvas_gather(
    const int4* __restrict__ idx4,         // ncells/4
    const float4* __restrict__ centers,    // P
    vfloat4* __restrict__ canvas4,         // bs*3*ncells4
    const int* __restrict__ xlp,
    const int* __restrict__ ylp,
    int ncells4)
{
    int i = blockIdx.x * 256 + threadIdx.x;
    if (i >= ncells4) return;

    const int cs4 = (*xlp * *ylp) >> 2;    // per-sample plane stride in float4
    const int b   = i / cs4;
    const int r4  = i - b * cs4;

    const int4 id = idx4[i];
    vfloat4 wx = {0.f, 0.f, 0.f, 0.f};
    vfloat4 wy = wx, wz = wx;
    if (id.x > 0) { float4 c = centers[id.x - 1]; wx.x = c.x; wy.x = c.y; wz.x = c.z; }
    if (id.y > 0) { float4 c = centers[id.y - 1]; wx.y = c.x; wy.y = c.y; wz.y = c.z; }
    if (id.z > 0) { float4 c = centers[id.z - 1]; wx.z = c.x; wy.z = c.y; wz.z = c.z; }
    if (id.w > 0) { float4 c = centers[id.w - 1]; wx.w = c.x; wy.w = c.y; wz.w = c.z; }

    // Canvas written exactly once, full-line, straight to HBM (NT keeps the
    // 20.6 MB out of L3 so idx/centers stay resident).
    const long base = (long)(b * 3) * cs4 + r4;
    __builtin_nontemporal_store(wx, &canvas4[base]);
    __builtin_nontemporal_store(wy, &canvas4[base + cs4]);
    __builtin_nontemporal_store(wz, &canvas4[base + 2 * cs4]);
}

// ---- Fallback path (ws too small): zero canvas + direct scatter (R5) ----
__global__ __launch_bounds__(256) void canvas_zero(float4* __restrict__ dst, long n4) {
    long i = (long)blockIdx.x * blockDim.x + threadIdx.x;
    const long stride = (long)gridDim.x * blockDim.x;
    const float4 z = make_float4(0.f, 0.f, 0.f, 0.f);
    for (; i < n4; i += stride) dst[i] = z;
}

__global__ __launch_bounds__(256) void pillar_fused_scatter(
    const vfloat4* __restrict__ pillars4, const int4* __restrict__ coors4,
    const int* __restrict__ npoints, const int* __restrict__ xlp,
    const int* __restrict__ ylp, vfloat4* __restrict__ out_pillars4,
    float4* __restrict__ out_coors4, float* __restrict__ out_np,
    float* __restrict__ canvas, int P)
{
    const int group = blockIdx.x * (blockDim.x >> 5) + (threadIdx.x >> 5);
    const int lane  = threadIdx.x & 31;
    if (group >= P) return;
    const int p = group;
    const vfloat4 v = __builtin_nontemporal_load(&pillars4[p * 32 + lane]);
    __builtin_nontemporal_store(v, &out_pillars4[p * 32 + lane]);
    float sx = v.x, sy = v.y, sz = v.z;
    #pragma unroll
    for (int m = 16; m >= 1; m >>= 1) {
        sx += __shfl_xor(sx, m);
        sy += __shfl_xor(sy, m);
        sz += __shfl_xor(sz, m);
    }
    if (lane < 3) {
        const int4 c = coors4[p];
        const int npts = npoints[p];
        const float s = (lane == 0) ? sx : (lane == 1) ? sy : sz;
        const int x_l = *xlp, y_l = *ylp;
        const long cs = (long)y_l * x_l;
        const long base = (long)c.x * 3l * cs + (long)c.z * x_l + (long)c.y;
        canvas[base + (long)lane * cs] = s / (float)npts;
        if (lane == 0) {
            out_coors4[p] = make_float4((float)c.x, (float)c.y, (float)c.z, (float)c.w);
            out_np[p] = (float)npts;
        }
    }
}

extern "C" void kernel_launch(void* const* d_in, const int* in_sizes, int n_in,
                              void* d_out, int out_size, void* d_ws, size_t ws_size,
                              hipStream_t stream) {
    const vfloat4* pillars4 = (const vfloat4*)d_in[0];
    const int4* coors4      = (const int4*)d_in[1];
    const int* npoints      = (const int*)d_in[2];
    const int* xlp = (const int*)d_in[4];
    const int* ylp = (const int*)d_in[5];

    const int n_pillars = in_sizes[0];   // P*128
    const int n_coors   = in_sizes[1];   // P*4
    const int P         = in_sizes[2];   // pillar count

    float* out            = (float*)d_out;
    vfloat4* out_pillars4 = (vfloat4*)out;
    float* out_coors      = out + n_pillars;
    float* out_np         = out_coors + n_coors;
    float* canvas         = out_np + P;
    const long canvas_elems = (long)out_size - n_pillars - n_coors - P;  // bs*3*ncells
    const long ncells       = canvas_elems / 3;                          // bs*y_l*x_l

    const size_t ws_need = (size_t)P * 16 + (size_t)ncells * 4;
    const int groups_per_block = 256 / 32;  // 8 pillars per block
    const int blocks = (P + groups_per_block - 1) / groups_per_block;

    if (ws_size >= ws_need && (ncells & 3) == 0) {
        float4* centers = (float4*)d_ws;
        int*    idx     = (int*)((char*)d_ws + (size_t)P * 16);
        const int ncells4 = (int)(ncells >> 2);

        idx_zero<<<(ncells4 + 255) / 256, 256, 0, stream>>>((int4*)idx, ncells4);
        pillar_fused<<<blocks, 256, 0, stream>>>(
            pillars4, coors4, npoints, xlp, ylp,
            out_pillars4, (float4*)out_coors, out_np, centers, idx, P);
        canvas_gather<<<(ncells4 + 255) / 256, 256, 0, stream>>>(
            (const int4*)idx, centers, (vfloat4*)canvas, xlp, ylp, ncells4);
    } else {
        const long n4 = canvas_elems >> 2;
        canvas_zero<<<(int)((n4 + 255) / 256), 256, 0, stream>>>((float4*)canvas, n4);
        pillar_fused_scatter<<<blocks, 256, 0, stream>>>(
            pillars4, coors4, npoints, xlp, ylp,
            out_pillars4, (float4*)out_coors, out_np, canvas, P);
    }
}

// Round 8
// 78.724 us; speedup vs baseline: 1.0725x; 1.0361x over previous
//
#include <hip/hip_runtime.h>

// PillarLayer: fused copy + per-pillar xyz center-of-mass + BEV canvas scatter.
//
// R8 = R5 (zero + direct scatter, NT streaming -- best so far, 76.7us) with
// 4x memory-level parallelism in the copy, WITHOUT breaking coalescing:
// each 32-lane group still owns one pillar per load instruction (wave64 =
// 1KB contiguous per instr), but each block now covers 32 pillars as K=4
// batches of 8, issuing all 4 independent 16B loads before any store.
// (R6 raised MLP by clustering 4 lanes/pillar and broke coalescing -> 84us.)
//
// Inputs: d_in[0] pillars f32 (P,32,4); d_in[1] coors int32 (P,4) [b,x,y,z];
//         d_in[2] npoints int32 (P); d_in[3] bs; d_in[4] x_l; d_in[5] y_l.
// Output (concat f32): pillars copy | coors as f32 | npoints as f32 |
//         canvas (bs,3,y_l,x_l) with canvas[b][c][y][x] = center_c or 0.

typedef float vfloat4 __attribute__((ext_vector_type(4)));

__global__ __launch_bounds__(256) void canvas_zero(float4* __restrict__ dst, long n4) {
    long i = (long)blockIdx.x * blockDim.x + threadIdx.x;
    const long stride = (long)gridDim.x * blockDim.x;
    const float4 z = make_float4(0.f, 0.f, 0.f, 0.f);
    for (; i < n4; i += stride) dst[i] = z;   // cacheable: L3-resident for scatter
}

__global__ __launch_bounds__(256) void pillar_fused(
    const vfloat4* __restrict__ pillars4,  // P*32 (one float4 per point)
    const int4* __restrict__ coors4,       // P [b,x,y,z]
    const int* __restrict__ npoints,       // P
    const int* __restrict__ xlp,           // scalar x_l
    const int* __restrict__ ylp,           // scalar y_l
    vfloat4* __restrict__ out_pillars4,    // P*32
    float4* __restrict__ out_coors4,       // P
    float* __restrict__ out_np,            // P
    float* __restrict__ canvas,            // bs*3*y_l*x_l
    int P)
{
    constexpr int K = 4;                       // pillar batches per block
    const int lane = threadIdx.x & 31;         // point index within pillar
    const int grp  = threadIdx.x >> 5;         // 0..7: pillar within batch
    const int p0   = blockIdx.x * (8 * K);     // block's first pillar

    const int x_l = *xlp;                      // scalar broadcast loads
    const int y_l = *ylp;
    const long cs = (long)y_l * (long)x_l;     // canvas plane stride

    // Phase 1: issue K independent NT loads back-to-back (4x MLP; each load
    // instruction is still 1KB contiguous per wave). NT keeps the 327 MB
    // stream out of L2/L3 so the zeroed canvas stays cache-resident.
    vfloat4 v[K];
    #pragma unroll
    for (int k = 0; k < K; ++k) {
        const int p = p0 + k * 8 + grp;
        if (p < P) v[k] = __builtin_nontemporal_load(&pillars4[(long)p * 32 + lane]);
    }

    // Phase 2: per batch: NT store copy, butterfly reduce, scatter.
    #pragma unroll
    for (int k = 0; k < K; ++k) {
        const int p = p0 + k * 8 + grp;
        if (p >= P) continue;

        __builtin_nontemporal_store(v[k], &out_pillars4[(long)p * 32 + lane]);

        float sx = v[k].x, sy = v[k].y, sz = v[k].z;
        #pragma unroll
        for (int m = 16; m >= 1; m >>= 1) {    // xor<32 stays in-group on wave64
            sx += __shfl_xor(sx, m);
            sy += __shfl_xor(sy, m);
            sz += __shfl_xor(sz, m);
        }

        if (lane < 3) {
            const int4 c   = coors4[p];        // same addr in group -> broadcast
            const int npts = npoints[p];
            const float s  = (lane == 0) ? sx : (lane == 1) ? sy : sz;
            const long base = (long)c.x * 3l * cs + (long)c.z * (long)x_l + (long)c.y;
            canvas[base + (long)lane * cs] = s / (float)npts;   // 3 planes, 3 lanes
            if (lane == 0) {
                out_coors4[p] = make_float4((float)c.x, (float)c.y, (float)c.z, (float)c.w);
                out_np[p]     = (float)npts;
            }
        }
    }
}

extern "C" void kernel_launch(void* const* d_in, const int* in_sizes, int n_in,
                              void* d_out, int out_size, void* d_ws, size_t ws_size,
                              hipStream_t stream) {
    const vfloat4* pillars4 = (const vfloat4*)d_in[0];
    const int4* coors4      = (const int4*)d_in[1];
    const int* npoints      = (const int*)d_in[2];
    const int* xlp = (const int*)d_in[4];
    const int* ylp = (const int*)d_in[5];

    const int n_pillars = in_sizes[0];   // P*128
    const int n_coors   = in_sizes[1];   // P*4
    const int P         = in_sizes[2];   // pillar count

    float* out            = (float*)d_out;
    vfloat4* out_pillars4 = (vfloat4*)out;
    float* out_coors      = out + n_pillars;
    float* out_np         = out_coors + n_coors;
    float* canvas         = out_np + P;
    const long canvas_elems = (long)out_size - n_pillars - n_coors - P;  // bs*3*y_l*x_l

    // K1: zero canvas (cacheable -> L3 resident for the scatter RMW).
    const long n4 = canvas_elems >> 2;   // canvas start is 16B-aligned here
    int zblocks = (int)((n4 + 511) / 512);
    if (zblocks > 2048) zblocks = 2048;
    canvas_zero<<<zblocks, 256, 0, stream>>>((float4*)canvas, n4);

    // K2: fused copy + reduce + scatter. 32 pillars per 256-thread block.
    const int blocks = (P + 31) / 32;
    pillar_fused<<<blocks, 256, 0, stream>>>(
        pillars4, coors4, npoints, xlp, ylp,
        out_pillars4, (float4*)out_coors, out_np, canvas, P);
}